// Round 1
// baseline (180.972 us; speedup 1.0000x reference)
//
#include <hip/hip_runtime.h>
#include <math.h>

#define BATCH 256
#define NQ    1000
#define NC    81
#define QC    81000   // NQ*NC
#define TOPK  100
#define NBINS 4096
#define CAP   4096
#define NT    1024

__device__ __forceinline__ float sigmoidf(float x) {
    // numerically-stable logistic, matching jax.nn.sigmoid's split
    if (x >= 0.f) {
        return 1.f / (1.f + expf(-x));
    } else {
        float e = expf(x);
        return e / (1.f + e);
    }
}

__global__ __launch_bounds__(NT) void postprocess_kernel(
    const float* __restrict__ logits,   // [B, Q, C]
    const float* __restrict__ obj,      // [B, Q]
    const float* __restrict__ boxes,    // [B, Q, 4] cx cy w h
    const float* __restrict__ unk,      // [B, Q]
    const float* __restrict__ tsz,      // [B, 2]  (h, w)
    float* __restrict__ out)            // scores[B*K] | labels[B*K] | boxes[B*K*4]
{
    __shared__ float    s_op[NQ];      // exp(-obj)
    __shared__ float    s_omun[NQ];    // 1 - sigmoid(unk)
    __shared__ float    s_last[NQ];    // exp(-obj) * sigmoid(unk)  (class 80)
    __shared__ unsigned s_hist[NBINS];
    __shared__ unsigned s_coarse[64];
    __shared__ float    s_cv[CAP];
    __shared__ int      s_ci[CAP];
    __shared__ unsigned s_cnt;
    __shared__ unsigned s_tbin;

    const int b   = blockIdx.x;
    const int tid = threadIdx.x;
    const float* lg = logits + (size_t)b * QC;

    // ---- init ----
    for (int i = tid; i < NBINS; i += NT) s_hist[i] = 0;
    if (tid == 0) s_cnt = 0;
    for (int q = tid; q < NQ; q += NT) {
        float op = expf(-obj[b * NQ + q]);
        float un = sigmoidf(unk[b * NQ + q]);
        s_op[q]   = op;
        s_omun[q] = 1.f - un;
        s_last[q] = op * un;
    }
    __syncthreads();

    // ---- pass 1: histogram of top-12 float bits (all probs >= 0) ----
    const float4* lg4 = (const float4*)lg;
    for (int i4 = tid; i4 < QC / 4; i4 += NT) {
        float4 v4 = lg4[i4];
        int e = i4 * 4;
        float xs[4] = {v4.x, v4.y, v4.z, v4.w};
        #pragma unroll
        for (int k = 0; k < 4; ++k) {
            int ee = e + k;
            int q = ee / NC;
            int c = ee - q * NC;
            if (c >= 60 && c < 80) continue;     // INVALID classes -> prob 0
            float v;
            if (c == 80) v = s_last[q];
            else         v = (s_op[q] * sigmoidf(xs[k])) * s_omun[q];
            unsigned u = __float_as_uint(v);
            atomicAdd(&s_hist[u >> 19], 1u);
        }
    }
    __syncthreads();

    // ---- find threshold bin (suffix count from top crosses TOPK) ----
    if (tid < 64) {
        unsigned s = 0;
        for (int j = 0; j < 64; ++j) s += s_hist[tid * 64 + j];
        s_coarse[tid] = s;
    }
    __syncthreads();
    if (tid == 0) {
        unsigned acc = 0;
        int cb = 0;
        for (int i = 63; i >= 0; --i) {
            if (acc + s_coarse[i] >= TOPK) { cb = i; break; }
            acc += s_coarse[i];
        }
        int tb = cb * 64;
        for (int f = cb * 64 + 63; f >= cb * 64; --f) {
            if (acc + s_hist[f] >= TOPK) { tb = f; break; }
            acc += s_hist[f];
        }
        s_tbin = (unsigned)tb;
    }
    __syncthreads();
    const unsigned thLo = s_tbin << 19;

    // ---- pass 2: collect candidates >= bin floor ----
    for (int i4 = tid; i4 < QC / 4; i4 += NT) {
        float4 v4 = lg4[i4];
        int e = i4 * 4;
        float xs[4] = {v4.x, v4.y, v4.z, v4.w};
        #pragma unroll
        for (int k = 0; k < 4; ++k) {
            int ee = e + k;
            int q = ee / NC;
            int c = ee - q * NC;
            if (c >= 60 && c < 80) continue;
            float v;
            if (c == 80) v = s_last[q];
            else         v = (s_op[q] * sigmoidf(xs[k])) * s_omun[q];
            if (__float_as_uint(v) >= thLo) {
                unsigned p = atomicAdd(&s_cnt, 1u);
                if (p < CAP) { s_cv[p] = v; s_ci[p] = ee; }
            }
        }
    }
    __syncthreads();

    const int n = (int)min(s_cnt, (unsigned)CAP);

    // ---- rank (exact, tie-break: lower flat index first, like lax.top_k) ----
    const float* bx = boxes + (size_t)b * NQ * 4;
    const float img_h = tsz[b * 2 + 0];
    const float img_w = tsz[b * 2 + 1];
    float* o_sc = out + (size_t)b * TOPK;
    float* o_lb = out + (size_t)BATCH * TOPK + (size_t)b * TOPK;
    float* o_bx = out + (size_t)2 * BATCH * TOPK + (size_t)b * TOPK * 4;

    for (int i = tid; i < n; i += NT) {
        float vi = s_cv[i];
        int   ei = s_ci[i];
        int r = 0;
        for (int j = 0; j < n; ++j) {
            float vj = s_cv[j];
            int   ej = s_ci[j];
            r += (vj > vi) || (vj == vi && ej < ei);
        }
        if (r < TOPK) {
            o_sc[r] = vi;
            o_lb[r] = (float)(ei % NC);
            int q = ei / NC;
            float cx = bx[q * 4 + 0];
            float cy = bx[q * 4 + 1];
            float w  = bx[q * 4 + 2];
            float h  = bx[q * 4 + 3];
            o_bx[r * 4 + 0] = (cx - 0.5f * w) * img_w;
            o_bx[r * 4 + 1] = (cy - 0.5f * h) * img_h;
            o_bx[r * 4 + 2] = (cx + 0.5f * w) * img_w;
            o_bx[r * 4 + 3] = (cy + 0.5f * h) * img_h;
        }
    }
}

extern "C" void kernel_launch(void* const* d_in, const int* in_sizes, int n_in,
                              void* d_out, int out_size, void* d_ws, size_t ws_size,
                              hipStream_t stream) {
    const float* pred_logits = (const float*)d_in[0];
    const float* pred_obj    = (const float*)d_in[1];
    const float* pred_boxes  = (const float*)d_in[2];
    const float* pred_unk    = (const float*)d_in[3];
    const float* target_sz   = (const float*)d_in[4];
    float* out = (float*)d_out;
    postprocess_kernel<<<BATCH, NT, 0, stream>>>(
        pred_logits, pred_obj, pred_boxes, pred_unk, target_sz, out);
}

// Round 2
// 157.446 us; speedup vs baseline: 1.1494x; 1.1494x over previous
//
#include <hip/hip_runtime.h>
#include <math.h>

#define BATCH 256
#define NQ    1000
#define NC    81
#define QC    81000   // NQ*NC
#define TOPK  100
#define NBINS 4096
#define CAP   4096
#define NT    1024

// Precise logistic, matching jax.nn.sigmoid's split (used only for the ~1000
// per-q factors and the few-hundred final candidates -> ranking is bit-identical
// to the known-passing absmax=0.0 kernel).
__device__ __forceinline__ float sigmoidf(float x) {
    if (x >= 0.f) {
        return 1.f / (1.f + expf(-x));
    } else {
        float e = expf(x);
        return e / (1.f + e);
    }
}

// Fast branch-free logistic: v_exp-based, ~1e-5 rel error, correct limits
// (x << 0 -> exp(-x)=inf -> rcp=0 ;  x >> 0 -> exp(-x)=0 -> rcp(1)=1).
__device__ __forceinline__ float fast_sig(float x) {
    return __builtin_amdgcn_rcpf(1.f + __expf(-x));
}

__global__ __launch_bounds__(NT) void postprocess_kernel(
    const float* __restrict__ logits,   // [B, Q, C]
    const float* __restrict__ obj,      // [B, Q]
    const float* __restrict__ boxes,    // [B, Q, 4] cx cy w h
    const float* __restrict__ unk,      // [B, Q]
    const float* __restrict__ tsz,      // [B, 2]  (h, w)
    float* __restrict__ out)            // scores[B*K] | labels[B*K] | boxes[B*K*4]
{
    __shared__ float    s_op[NQ];      // exp(-obj)            (precise)
    __shared__ float    s_omun[NQ];    // 1 - sigmoid(unk)     (precise)
    __shared__ float    s_last[NQ];    // exp(-obj)*sigmoid(unk)  class 80 (precise)
    __shared__ unsigned s_hist[NBINS];
    __shared__ unsigned s_coarse[64];
    __shared__ float    s_cv[CAP];
    __shared__ int      s_ci[CAP];
    __shared__ unsigned s_cnt;
    __shared__ unsigned s_tbin;

    const int b   = blockIdx.x;
    const int tid = threadIdx.x;
    const float* lg = logits + (size_t)b * QC;

    // ---- init ----
    for (int i = tid; i < NBINS; i += NT) s_hist[i] = 0;
    if (tid == 0) s_cnt = 0;
    for (int q = tid; q < NQ; q += NT) {
        float op = expf(-obj[b * NQ + q]);
        float un = sigmoidf(unk[b * NQ + q]);
        s_op[q]   = op;
        s_omun[q] = 1.f - un;
        s_last[q] = op * un;
    }
    __syncthreads();

    // ---- pass 1: approx-score histogram of top-12 float bits (probs >= 0) ----
    const float4* lg4 = (const float4*)lg;
    for (int i4 = tid; i4 < QC / 4; i4 += NT) {
        float4 v4 = lg4[i4];
        int e = i4 * 4;
        float xs[4] = {v4.x, v4.y, v4.z, v4.w};
        #pragma unroll
        for (int k = 0; k < 4; ++k) {
            int ee = e + k;
            int q = ee / NC;
            int c = ee - q * NC;
            if (c >= 60 && c < 80) continue;     // INVALID classes -> prob 0
            float v;
            if (c == 80) v = s_last[q];
            else         v = (s_op[q] * fast_sig(xs[k])) * s_omun[q];
            unsigned u = __float_as_uint(v);
            atomicAdd(&s_hist[u >> 19], 1u);
        }
    }
    __syncthreads();

    // ---- find threshold bin (suffix count from top crosses TOPK) ----
    if (tid < 64) {
        unsigned s = 0;
        for (int j = 0; j < 64; ++j) s += s_hist[tid * 64 + j];
        s_coarse[tid] = s;
    }
    __syncthreads();
    if (tid == 0) {
        unsigned acc = 0;
        int cb = 0;
        for (int i = 63; i >= 0; --i) {
            if (acc + s_coarse[i] >= TOPK) { cb = i; break; }
            acc += s_coarse[i];
        }
        int tb = cb * 64;
        for (int f = cb * 64 + 63; f >= cb * 64; --f) {
            if (acc + s_hist[f] >= TOPK) { tb = f; break; }
            acc += s_hist[f];
        }
        s_tbin = (unsigned)tb;
    }
    __syncthreads();
    // Lower by one full bin (~6% relative margin) so the approx filter provably
    // keeps every true top-100 element despite ~1e-5 fast-sigmoid error.
    const unsigned tbM  = (s_tbin > 0) ? (s_tbin - 1) : 0;
    const unsigned thLo = tbM << 19;

    // ---- pass 2: approx filter; PRECISE score stored for candidates ----
    for (int i4 = tid; i4 < QC / 4; i4 += NT) {
        float4 v4 = lg4[i4];
        int e = i4 * 4;
        float xs[4] = {v4.x, v4.y, v4.z, v4.w};
        #pragma unroll
        for (int k = 0; k < 4; ++k) {
            int ee = e + k;
            int q = ee / NC;
            int c = ee - q * NC;
            if (c >= 60 && c < 80) continue;
            float va;
            if (c == 80) va = s_last[q];
            else         va = (s_op[q] * fast_sig(xs[k])) * s_omun[q];
            if (__float_as_uint(va) >= thLo) {
                float v;  // precise score, same op order as the absmax=0 kernel
                if (c == 80) v = s_last[q];
                else         v = (s_op[q] * sigmoidf(xs[k])) * s_omun[q];
                unsigned p = atomicAdd(&s_cnt, 1u);
                if (p < CAP) { s_cv[p] = v; s_ci[p] = ee; }
            }
        }
    }
    __syncthreads();

    const int n = (int)min(s_cnt, (unsigned)CAP);

    // ---- rank (exact, tie-break: lower flat index first, like lax.top_k) ----
    const float* bx = boxes + (size_t)b * NQ * 4;
    const float img_h = tsz[b * 2 + 0];
    const float img_w = tsz[b * 2 + 1];
    float* o_sc = out + (size_t)b * TOPK;
    float* o_lb = out + (size_t)BATCH * TOPK + (size_t)b * TOPK;
    float* o_bx = out + (size_t)2 * BATCH * TOPK + (size_t)b * TOPK * 4;

    for (int i = tid; i < n; i += NT) {
        float vi = s_cv[i];
        int   ei = s_ci[i];
        int r = 0;
        for (int j = 0; j < n; ++j) {
            float vj = s_cv[j];
            int   ej = s_ci[j];
            r += (vj > vi) || (vj == vi && ej < ei);
        }
        if (r < TOPK) {
            o_sc[r] = vi;
            o_lb[r] = (float)(ei % NC);
            int q = ei / NC;
            float cx = bx[q * 4 + 0];
            float cy = bx[q * 4 + 1];
            float w  = bx[q * 4 + 2];
            float h  = bx[q * 4 + 3];
            o_bx[r * 4 + 0] = (cx - 0.5f * w) * img_w;
            o_bx[r * 4 + 1] = (cy - 0.5f * h) * img_h;
            o_bx[r * 4 + 2] = (cx + 0.5f * w) * img_w;
            o_bx[r * 4 + 3] = (cy + 0.5f * h) * img_h;
        }
    }
}

extern "C" void kernel_launch(void* const* d_in, const int* in_sizes, int n_in,
                              void* d_out, int out_size, void* d_ws, size_t ws_size,
                              hipStream_t stream) {
    const float* pred_logits = (const float*)d_in[0];
    const float* pred_obj    = (const float*)d_in[1];
    const float* pred_boxes  = (const float*)d_in[2];
    const float* pred_unk    = (const float*)d_in[3];
    const float* target_sz   = (const float*)d_in[4];
    float* out = (float*)d_out;
    postprocess_kernel<<<BATCH, NT, 0, stream>>>(
        pred_logits, pred_obj, pred_boxes, pred_unk, target_sz, out);
}